// Round 8
// baseline (273.813 us; speedup 1.0000x reference)
//
#include <hip/hip_runtime.h>
#include <hip/hip_bf16.h>

#define C 128

typedef short s16x8 __attribute__((ext_vector_type(8)));
typedef float f32x4 __attribute__((ext_vector_type(4)));

static __device__ __forceinline__ float b2f(unsigned short u) {
    union { unsigned int i; float f; } v;
    v.i = ((unsigned int)u) << 16;
    return v.f;
}
static __device__ __forceinline__ unsigned short f2b(float f) {
    __hip_bfloat16 b = __float2bfloat16(f);   // RNE
    return *reinterpret_cast<unsigned short*>(&b);
}

// ---------------- zero ints (int4) ----------------
__global__ __launch_bounds__(256) void zero_int_kernel(int4* __restrict__ p, long n4) {
    long i = blockIdx.x * 256L + threadIdx.x;
    if (i < n4) p[i] = make_int4(0, 0, 0, 0);
}

// ---------------- degree histograms, 4 edges/thread ----------------
__global__ __launch_bounds__(256) void hist_kernel(
    const int* __restrict__ ei, int E,
    int* __restrict__ degs, int* __restrict__ degd) {
    int i = blockIdx.x * 256 + threadIdx.x;
    int e0 = i * 4;
    if (e0 + 4 <= E) {
        int4 s = *(const int4*)(ei + e0);
        int4 d = *(const int4*)(ei + E + e0);
        atomicAdd(&degs[s.x], 1); atomicAdd(&degs[s.y], 1);
        atomicAdd(&degs[s.z], 1); atomicAdd(&degs[s.w], 1);
        atomicAdd(&degd[d.x], 1); atomicAdd(&degd[d.y], 1);
        atomicAdd(&degd[d.z], 1); atomicAdd(&degd[d.w], 1);
    } else {
        for (int e = e0; e < E; ++e) {
            atomicAdd(&degs[ei[e]], 1);
            atomicAdd(&degd[ei[E + e]], 1);
        }
    }
}

// ---------------- W transpose -> bf16 + coef (one-time, tiny) ----------------
__global__ __launch_bounds__(256) void wt_kernel(const float* __restrict__ W,
                                                 unsigned short* __restrict__ WtB,
                                                 const float* __restrict__ log_scale,
                                                 const float* __restrict__ hop_logits,
                                                 float* __restrict__ coef) {
    int tid = blockIdx.x * 256 + threadIdx.x;   // 16384 threads
    int k = tid & 127, c = tid >> 7;
    WtB[c * 128 + k] = f2b(W[k * 128 + c]);
    if (tid == 0) {
        float s = expf(log_scale[0]);
        float m = hop_logits[0];
        for (int kk = 1; kk < 4; ++kk) m = fmaxf(m, hop_logits[kk]);
        float a[4], sum = 0.0f;
        for (int kk = 0; kk < 4; ++kk) { a[kk] = expf(hop_logits[kk] - m); sum += a[kk]; }
        for (int kk = 0; kk < 4; ++kk) coef[kk] = (a[kk] / sum) * expf(-s * (float)kk);
    }
}

// ---------------- scan stage 1 ----------------
__global__ __launch_bounds__(256) void scan1_kernel(const int* __restrict__ degd,
                                                    int* __restrict__ rp,
                                                    int* __restrict__ bsum, int N) {
    __shared__ int sm[256];
    int t = threadIdx.x;
    int i = blockIdx.x * 256 + t;
    int v = (i < N) ? degd[i] : 0;
    sm[t] = v;
    __syncthreads();
    for (int off = 1; off < 256; off <<= 1) {
        int add = (t >= off) ? sm[t - off] : 0;
        __syncthreads();
        sm[t] += add;
        __syncthreads();
    }
    if (i < N) rp[i] = sm[t] - v;
    if (t == 255) bsum[blockIdx.x] = sm[255];
}

// ---------------- scan stage 2 ----------------
__global__ __launch_bounds__(512) void scan2_kernel(int* __restrict__ bsum, int nb) {
    __shared__ int sm[512];
    int t = threadIdx.x;
    int v = (t < nb) ? bsum[t] : 0;
    sm[t] = v;
    __syncthreads();
    for (int off = 1; off < 512; off <<= 1) {
        int add = (t >= off) ? sm[t - off] : 0;
        __syncthreads();
        sm[t] += add;
        __syncthreads();
    }
    if (t < nb) bsum[t] = sm[t] - v;
}

// ---------------- scan stage 3: offsets + cursor + dsi/ddi; rp[N]=E ----------------
__global__ __launch_bounds__(256) void scan3_kernel(int* __restrict__ rp,
                                                    const int* __restrict__ bsum,
                                                    int* __restrict__ cursor,
                                                    const int* __restrict__ degs,
                                                    const int* __restrict__ degd,
                                                    float* __restrict__ dsi,
                                                    float* __restrict__ ddi,
                                                    int N, int E) {
    int i = blockIdx.x * 256 + threadIdx.x;
    if (i < N) {
        int v = rp[i] + bsum[i >> 8];
        rp[i] = v;
        cursor[i] = v;
        int ds = degs[i];
        dsi[i] = ds > 0 ? rsqrtf((float)ds) : 0.0f;
        int dd = degd[i];
        ddi[i] = dd > 0 ? rsqrtf((float)dd) : 0.0f;
    }
    if (i == 0) rp[N] = E;
}

// ---------------- scatter edges into CSR (by dst), 4 edges/thread ----------------
__global__ __launch_bounds__(256) void scatter_kernel(const int* __restrict__ ei, int E,
                                                      int* __restrict__ cursor,
                                                      const float* __restrict__ dsi,
                                                      int2* __restrict__ csr) {
    int i = blockIdx.x * 256 + threadIdx.x;
    int e0 = i * 4;
    if (e0 + 4 <= E) {
        int4 s = *(const int4*)(ei + e0);
        int4 d = *(const int4*)(ei + E + e0);
        int p0 = atomicAdd(&cursor[d.x], 1);
        int p1 = atomicAdd(&cursor[d.y], 1);
        int p2 = atomicAdd(&cursor[d.z], 1);
        int p3 = atomicAdd(&cursor[d.w], 1);
        csr[p0] = make_int2(s.x, __float_as_int(dsi[s.x]));
        csr[p1] = make_int2(s.y, __float_as_int(dsi[s.y]));
        csr[p2] = make_int2(s.z, __float_as_int(dsi[s.z]));
        csr[p3] = make_int2(s.w, __float_as_int(dsi[s.w]));
    } else {
        for (int e = e0; e < E; ++e) {
            int s = ei[e];
            int d = ei[E + e];
            int pos = atomicAdd(&cursor[d], 1);
            csr[pos] = make_int2(s, __float_as_int(dsi[s]));
        }
    }
}

// ---------------- pull-mode hop: one wave per dst node, 8-wide predicated ----------------
template<int SRCF32>
__global__ __launch_bounds__(256) void pull_kernel(
    const int* __restrict__ rp, const int2* __restrict__ csr,
    const float* __restrict__ ddi,
    const void* __restrict__ cur, unsigned int* __restrict__ nxt, int N) {
    int wid = (int)((blockIdx.x * 256L + threadIdx.x) >> 6);
    if (wid >= N) return;
    int lane = threadIdx.x & 63;
    int beg = __builtin_amdgcn_readfirstlane(rp[wid]);
    int end = __builtin_amdgcn_readfirstlane(rp[wid + 1]);
    const float2* curf = (const float2*)cur;
    const unsigned int* curb = (const unsigned int*)cur;
    float sx = 0.f, sy = 0.f;
    if (beg < end) {
        for (int j = beg; j < end; j += 8) {
            int   idx[8];
            float wt[8];
            #pragma unroll
            for (int i = 0; i < 8; ++i) {
                int jj = j + i;
                bool ok = jj < end;
                int2 e = csr[ok ? jj : beg];
                idx[i] = e.x;
                wt[i] = ok ? __int_as_float(e.y) : 0.0f;
            }
            if (SRCF32) {
                float2 v[8];
                #pragma unroll
                for (int i = 0; i < 8; ++i) v[i] = curf[(long)idx[i] * 64 + lane];
                #pragma unroll
                for (int i = 0; i < 8; ++i) { sx += wt[i] * v[i].x; sy += wt[i] * v[i].y; }
            } else {
                unsigned int u[8];
                #pragma unroll
                for (int i = 0; i < 8; ++i) u[i] = curb[(long)idx[i] * 64 + lane];
                #pragma unroll
                for (int i = 0; i < 8; ++i) {
                    sx += wt[i] * b2f((unsigned short)(u[i] & 0xffff));
                    sy += wt[i] * b2f((unsigned short)(u[i] >> 16));
                }
            }
        }
        float dv = ddi[wid];
        sx *= dv; sy *= dv;
    }
    unsigned int o = (unsigned int)f2b(sx) | ((unsigned int)f2b(sy) << 16);
    nxt[(long)wid * 64 + lane] = o;
}

// ---------------- fused pull3 + combine + matmul ----------------
// 512 threads = 8 waves; wave w: gather h3 row for dst (blk*8+w), combine with
// streamed x/h1/h2 rows -> bf16 -> LDS row w (rows 8..15 zeroed); barrier;
// wave w MFMAs the 16x128 tile vs W^T cols [16w,16w+16) read from global (L1-hot).
__global__ __launch_bounds__(512, 6) void pull3_mm_kernel(
    const int* __restrict__ rp, const int2* __restrict__ csr,
    const float* __restrict__ ddi,
    const float* __restrict__ x,
    const unsigned short* __restrict__ h1,
    const unsigned short* __restrict__ h2,
    const float* __restrict__ coef,
    const unsigned short* __restrict__ WtB,
    const float* __restrict__ bias,
    float* __restrict__ out, int N) {
    __shared__ unsigned short Xl[16 * 136];   // 4352 B, padded rows
    int t = threadIdx.x;
    int w = t >> 6, lane = t & 63;
    int wid = blockIdx.x * 8 + w;
    float c0 = coef[0], c1 = coef[1], c2 = coef[2], c3 = coef[3];

    float sx = 0.f, sy = 0.f;
    if (wid < N) {
        int beg = __builtin_amdgcn_readfirstlane(rp[wid]);
        int end = __builtin_amdgcn_readfirstlane(rp[wid + 1]);
        const unsigned int* curb = (const unsigned int*)h2;
        if (beg < end) {
            for (int j = beg; j < end; j += 8) {
                int   idx[8];
                float wt[8];
                #pragma unroll
                for (int i = 0; i < 8; ++i) {
                    int jj = j + i;
                    bool ok = jj < end;
                    int2 e = csr[ok ? jj : beg];
                    idx[i] = e.x;
                    wt[i] = ok ? __int_as_float(e.y) : 0.0f;
                }
                unsigned int u[8];
                #pragma unroll
                for (int i = 0; i < 8; ++i) u[i] = curb[(long)idx[i] * 64 + lane];
                #pragma unroll
                for (int i = 0; i < 8; ++i) {
                    sx += wt[i] * b2f((unsigned short)(u[i] & 0xffff));
                    sy += wt[i] * b2f((unsigned short)(u[i] >> 16));
                }
            }
            float dv = ddi[wid];
            sx *= dv; sy *= dv;
        }
        // combine with streamed x, h1, h2 rows (h3 = sx,sy in registers, f32)
        long rbase = (long)wid * C;
        float2 xv = ((const float2*)(x + rbase))[lane];
        unsigned int u1 = ((const unsigned int*)(h1 + rbase))[lane];
        unsigned int u2 = ((const unsigned int*)(h2 + rbase))[lane];
        float f0 = c0 * xv.x + c1 * b2f((unsigned short)(u1 & 0xffff))
                 + c2 * b2f((unsigned short)(u2 & 0xffff)) + c3 * sx;
        float f1 = c0 * xv.y + c1 * b2f((unsigned short)(u1 >> 16))
                 + c2 * b2f((unsigned short)(u2 >> 16)) + c3 * sy;
        sx = f0; sy = f1;
    } else {
        sx = 0.f; sy = 0.f;
    }
    unsigned int pk = (unsigned int)f2b(sx) | ((unsigned int)f2b(sy) << 16);
    *(unsigned int*)(Xl + w * 136 + lane * 2) = pk;          // row w
    *(unsigned int*)(Xl + (w + 8) * 136 + lane * 2) = 0u;    // zero row w+8
    __syncthreads();

    // matmul phase: wave w -> out cols [16w, 16w+16)
    int lsel = lane & 15;
    int lk = (lane >> 4) * 8;
    f32x4 acc = (f32x4){0.f, 0.f, 0.f, 0.f};
    #pragma unroll
    for (int ks = 0; ks < 4; ++ks) {
        int k0 = ks * 32 + lk;
        s16x8 a = *(const s16x8*)(Xl + lsel * 136 + k0);
        s16x8 b = *(const s16x8*)(WtB + (w * 16 + lsel) * 128 + k0);
        acc = __builtin_amdgcn_mfma_f32_16x16x32_bf16(a, b, acc, 0, 0, 0);
    }
    int r0 = (lane >> 4) * 4;          // D rows r0..r0+3 (valid only < 8)
    int ocol = w * 16 + lsel;
    float bv = bias[ocol];
    #pragma unroll
    for (int r = 0; r < 4; ++r) {
        int row = r0 + r;
        if (row < 8) {
            int orow = blockIdx.x * 8 + row;
            if (orow < N) out[(long)orow * C + ocol] = acc[r] + bv;
        }
    }
}

extern "C" void kernel_launch(void* const* d_in, const int* in_sizes, int n_in,
                              void* d_out, int out_size, void* d_ws, size_t ws_size,
                              hipStream_t stream) {
    const float* x          = (const float*)d_in[0];
    const int*   ei         = (const int*)d_in[1];   // harness delivers int32
    const float* W          = (const float*)d_in[3];
    const float* bias       = (const float*)d_in[4];
    const float* log_scale  = (const float*)d_in[5];
    const float* hop_logits = (const float*)d_in[6];
    float* out = (float*)d_out;

    int N = in_sizes[0] / C;
    int E = in_sizes[1] / 2;

    char* ws = (char*)d_ws;
    size_t hb = (size_t)N * C * sizeof(unsigned short);  // 25.6 MB per bf16 hop buffer
    unsigned short* h1 = (unsigned short*)ws;
    unsigned short* h2 = (unsigned short*)(ws + hb);
    int2*  csr     = (int2*)(ws + 2 * hb);            // E entries
    int*   degs    = (int*)(csr + E);
    int*   degd    = degs + N;
    int*   rp      = degd + N;            // N+1
    int*   cursor  = rp + N + 1;
    float* dsi     = (float*)(cursor + N);
    float* ddi     = dsi + N;
    int*   bsum    = (int*)(ddi + N);     // 512
    float* coef    = (float*)(bsum + 512);
    unsigned short* WtB = (unsigned short*)(coef + 4);  // 128*128 bf16

    int eb4 = (E / 4 + 255) / 256 + 1;    // 4 edges/thread kernels
    int nbk = (N + 255) / 256;
    int pull_blocks = (int)(((long)N * 64 + 255) / 256);

    // CSR build + W transpose + coef
    zero_int_kernel<<<(int)((2L * N / 4 + 255) / 256), 256, 0, stream>>>((int4*)degs, 2L * N / 4);
    hist_kernel<<<eb4, 256, 0, stream>>>(ei, E, degs, degd);
    wt_kernel<<<64, 256, 0, stream>>>(W, WtB, log_scale, hop_logits, coef);
    scan1_kernel<<<nbk, 256, 0, stream>>>(degd, rp, bsum, N);
    scan2_kernel<<<1, 512, 0, stream>>>(bsum, nbk);
    scan3_kernel<<<nbk, 256, 0, stream>>>(rp, bsum, cursor, degs, degd, dsi, ddi, N, E);
    scatter_kernel<<<eb4, 256, 0, stream>>>(ei, E, cursor, dsi, csr);

    // hops 1,2: predicated 8-wide gather -> bf16 write
    pull_kernel<1><<<pull_blocks, 256, 0, stream>>>(rp, csr, ddi, x,  (unsigned int*)h1, N);
    pull_kernel<0><<<pull_blocks, 256, 0, stream>>>(rp, csr, ddi, h1, (unsigned int*)h2, N);

    // hop 3 fused with combine + matmul: out = (c0*x + c1*h1 + c2*h2 + c3*h3) @ W + bias
    pull3_mm_kernel<<<(N + 7) / 8, 512, 0, stream>>>(rp, csr, ddi, x, h1, h2,
                                                     coef, WtB, bias, out, N);
}

// Round 9
// 262.828 us; speedup vs baseline: 1.0418x; 1.0418x over previous
//
#include <hip/hip_runtime.h>
#include <hip/hip_bf16.h>

#define C 128
#define WELL 32   // ELL width (max in-degree supported; Poisson(6) => P(>31) ~ 1e-13)

typedef short s16x8 __attribute__((ext_vector_type(8)));
typedef float f32x4 __attribute__((ext_vector_type(4)));

static __device__ __forceinline__ float b2f(unsigned short u) {
    union { unsigned int i; float f; } v;
    v.i = ((unsigned int)u) << 16;
    return v.f;
}
static __device__ __forceinline__ unsigned short f2b(float f) {
    __hip_bfloat16 b = __float2bfloat16(f);   // RNE
    return *reinterpret_cast<unsigned short*>(&b);
}

// ---------------- zero ints (int4) ----------------
__global__ __launch_bounds__(256) void zero_int_kernel(int4* __restrict__ p, long n4) {
    long i = blockIdx.x * 256L + threadIdx.x;
    if (i < n4) p[i] = make_int4(0, 0, 0, 0);
}

// ---------------- degree histograms, 4 edges/thread ----------------
__global__ __launch_bounds__(256) void hist_kernel(
    const int* __restrict__ ei, int E,
    int* __restrict__ degs, int* __restrict__ degd) {
    int i = blockIdx.x * 256 + threadIdx.x;
    int e0 = i * 4;
    if (e0 + 4 <= E) {
        int4 s = *(const int4*)(ei + e0);
        int4 d = *(const int4*)(ei + E + e0);
        atomicAdd(&degs[s.x], 1); atomicAdd(&degs[s.y], 1);
        atomicAdd(&degs[s.z], 1); atomicAdd(&degs[s.w], 1);
        atomicAdd(&degd[d.x], 1); atomicAdd(&degd[d.y], 1);
        atomicAdd(&degd[d.z], 1); atomicAdd(&degd[d.w], 1);
    } else {
        for (int e = e0; e < E; ++e) {
            atomicAdd(&degs[ei[e]], 1);
            atomicAdd(&degd[ei[E + e]], 1);
        }
    }
}

// ---------------- W transpose -> bf16 + coef (one-time, tiny) ----------------
__global__ __launch_bounds__(256) void wt_kernel(const float* __restrict__ W,
                                                 unsigned short* __restrict__ WtB,
                                                 const float* __restrict__ log_scale,
                                                 const float* __restrict__ hop_logits,
                                                 float* __restrict__ coef) {
    int tid = blockIdx.x * 256 + threadIdx.x;   // 16384 threads
    int k = tid & 127, c = tid >> 7;
    WtB[c * 128 + k] = f2b(W[k * 128 + c]);
    if (tid == 0) {
        float s = expf(log_scale[0]);
        float m = hop_logits[0];
        for (int kk = 1; kk < 4; ++kk) m = fmaxf(m, hop_logits[kk]);
        float a[4], sum = 0.0f;
        for (int kk = 0; kk < 4; ++kk) { a[kk] = expf(hop_logits[kk] - m); sum += a[kk]; }
        for (int kk = 0; kk < 4; ++kk) coef[kk] = (a[kk] / sum) * expf(-s * (float)kk);
    }
}

// ---------------- scatter edges into ELL (by dst), weight computed inline ----------------
// slot = atomicAdd(cursor[d]); ell[d*WELL + slot] = (src, rsqrt(deg_src))
__global__ __launch_bounds__(256) void scatter_kernel(const int* __restrict__ ei, int E,
                                                      int* __restrict__ cursor,
                                                      const int* __restrict__ degs,
                                                      int2* __restrict__ ell) {
    int i = blockIdx.x * 256 + threadIdx.x;
    int e0 = i * 4;
    if (e0 + 4 <= E) {
        int4 s = *(const int4*)(ei + e0);
        int4 d = *(const int4*)(ei + E + e0);
        float w0 = rsqrtf((float)degs[s.x]);   // deg_src >= 1 by construction
        float w1 = rsqrtf((float)degs[s.y]);
        float w2 = rsqrtf((float)degs[s.z]);
        float w3 = rsqrtf((float)degs[s.w]);
        int p0 = atomicAdd(&cursor[d.x], 1);
        int p1 = atomicAdd(&cursor[d.y], 1);
        int p2 = atomicAdd(&cursor[d.z], 1);
        int p3 = atomicAdd(&cursor[d.w], 1);
        if (p0 < WELL) ell[(long)d.x * WELL + p0] = make_int2(s.x, __float_as_int(w0));
        if (p1 < WELL) ell[(long)d.y * WELL + p1] = make_int2(s.y, __float_as_int(w1));
        if (p2 < WELL) ell[(long)d.z * WELL + p2] = make_int2(s.z, __float_as_int(w2));
        if (p3 < WELL) ell[(long)d.w * WELL + p3] = make_int2(s.w, __float_as_int(w3));
    } else {
        for (int e = e0; e < E; ++e) {
            int s = ei[e];
            int d = ei[E + e];
            float w = rsqrtf((float)degs[s]);
            int pos = atomicAdd(&cursor[d], 1);
            if (pos < WELL) ell[(long)d * WELL + pos] = make_int2(s, __float_as_int(w));
        }
    }
}

// ---------------- pull-mode hop: one wave per dst node, 8-wide predicated, ELL ----------------
// nxt[n] = bf16( rsqrt(deg_d[n]) * sum_{e in in(n)} w_e * cur[src_e] )
template<int SRCF32>
__global__ __launch_bounds__(256) void pull_kernel(
    const int2* __restrict__ ell, const int* __restrict__ degd,
    const void* __restrict__ cur, unsigned int* __restrict__ nxt, int N) {
    int wid = (int)((blockIdx.x * 256L + threadIdx.x) >> 6);
    if (wid >= N) return;
    int lane = threadIdx.x & 63;
    int cnt = __builtin_amdgcn_readfirstlane(degd[wid]);
    cnt = cnt < WELL ? cnt : WELL;
    long base = (long)wid * WELL;
    const float2* curf = (const float2*)cur;
    const unsigned int* curb = (const unsigned int*)cur;
    float sx = 0.f, sy = 0.f;
    if (cnt > 0) {
        for (int j = 0; j < cnt; j += 8) {
            int   idx[8];
            float wt[8];
            #pragma unroll
            for (int i = 0; i < 8; ++i) {
                int jj = j + i;
                bool ok = jj < cnt;
                int2 e = ell[base + (ok ? jj : 0)];
                idx[i] = e.x;
                wt[i] = ok ? __int_as_float(e.y) : 0.0f;
            }
            if (SRCF32) {
                float2 v[8];
                #pragma unroll
                for (int i = 0; i < 8; ++i) v[i] = curf[(long)idx[i] * 64 + lane];
                #pragma unroll
                for (int i = 0; i < 8; ++i) { sx += wt[i] * v[i].x; sy += wt[i] * v[i].y; }
            } else {
                unsigned int u[8];
                #pragma unroll
                for (int i = 0; i < 8; ++i) u[i] = curb[(long)idx[i] * 64 + lane];
                #pragma unroll
                for (int i = 0; i < 8; ++i) {
                    sx += wt[i] * b2f((unsigned short)(u[i] & 0xffff));
                    sy += wt[i] * b2f((unsigned short)(u[i] >> 16));
                }
            }
        }
        float dv = rsqrtf((float)cnt);
        sx *= dv; sy *= dv;
    }
    unsigned int o = (unsigned int)f2b(sx) | ((unsigned int)f2b(sy) << 16);
    nxt[(long)wid * 64 + lane] = o;
}

// ---------------- MFMA matmul: out = (c0*x + c1*h1 + c2*h2 + c3*h3) @ W + bias ----------------
// 64 rows/block, 4 waves; A built in registers from global; B (W^T bf16) in LDS (136-padded).
__global__ __launch_bounds__(256) void mfma_matmul_kernel(
    const float* __restrict__ x,
    const unsigned short* __restrict__ h1,
    const unsigned short* __restrict__ h2,
    const unsigned short* __restrict__ h3,
    const float* __restrict__ coef,
    const unsigned short* __restrict__ WtB,
    const float* __restrict__ bias,
    float* __restrict__ out, int N) {
    __shared__ unsigned short Wl[128 * 136];   // 34816 B, padded rows
    int t = threadIdx.x;

    #pragma unroll
    for (int i = 0; i < 8; ++i) {
        int ch = t + i * 256;          // 0..2047
        int r = ch >> 4;               // 0..127 (col of W)
        int ko = (ch & 15) * 8;        // k offset
        *(s16x8*)(Wl + r * 136 + ko) = *(const s16x8*)(WtB + r * 128 + ko);
    }
    float c0 = coef[0], c1 = coef[1], c2 = coef[2], c3 = coef[3];
    __syncthreads();

    int wave = t >> 6, lane = t & 63;
    int lsel = lane & 15;
    int lk   = (lane >> 4) * 8;
    int arow = blockIdx.x * 64 + wave * 16 + lsel;
    bool rok = arow < N;
    long rbase = (long)arow * C;

    f32x4 acc[8];
    #pragma unroll
    for (int i = 0; i < 8; ++i) acc[i] = (f32x4){0.f, 0.f, 0.f, 0.f};

    #pragma unroll
    for (int ks = 0; ks < 4; ++ks) {
        int k0 = ks * 32 + lk;
        s16x8 a;
        if (rok) {
            const float* xp = x + rbase + k0;
            float4 xa = *(const float4*)xp;
            float4 xb = *(const float4*)(xp + 4);
            s16x8 u1 = *(const s16x8*)(h1 + rbase + k0);
            s16x8 u2 = *(const s16x8*)(h2 + rbase + k0);
            s16x8 u3 = *(const s16x8*)(h3 + rbase + k0);
            float f0 = c0 * xa.x + c1 * b2f((unsigned short)u1[0]) + c2 * b2f((unsigned short)u2[0]) + c3 * b2f((unsigned short)u3[0]);
            float f1 = c0 * xa.y + c1 * b2f((unsigned short)u1[1]) + c2 * b2f((unsigned short)u2[1]) + c3 * b2f((unsigned short)u3[1]);
            float f2 = c0 * xa.z + c1 * b2f((unsigned short)u1[2]) + c2 * b2f((unsigned short)u2[2]) + c3 * b2f((unsigned short)u3[2]);
            float f3 = c0 * xa.w + c1 * b2f((unsigned short)u1[3]) + c2 * b2f((unsigned short)u2[3]) + c3 * b2f((unsigned short)u3[3]);
            float f4 = c0 * xb.x + c1 * b2f((unsigned short)u1[4]) + c2 * b2f((unsigned short)u2[4]) + c3 * b2f((unsigned short)u3[4]);
            float f5 = c0 * xb.y + c1 * b2f((unsigned short)u1[5]) + c2 * b2f((unsigned short)u2[5]) + c3 * b2f((unsigned short)u3[5]);
            float f6 = c0 * xb.z + c1 * b2f((unsigned short)u1[6]) + c2 * b2f((unsigned short)u2[6]) + c3 * b2f((unsigned short)u3[6]);
            float f7 = c0 * xb.w + c1 * b2f((unsigned short)u1[7]) + c2 * b2f((unsigned short)u2[7]) + c3 * b2f((unsigned short)u3[7]);
            a[0] = (short)f2b(f0); a[1] = (short)f2b(f1);
            a[2] = (short)f2b(f2); a[3] = (short)f2b(f3);
            a[4] = (short)f2b(f4); a[5] = (short)f2b(f5);
            a[6] = (short)f2b(f6); a[7] = (short)f2b(f7);
        } else {
            a = (s16x8)0;
        }
        #pragma unroll
        for (int cf = 0; cf < 8; ++cf) {
            s16x8 b = *(const s16x8*)(Wl + (cf * 16 + lsel) * 136 + k0);
            acc[cf] = __builtin_amdgcn_mfma_f32_16x16x32_bf16(a, b, acc[cf], 0, 0, 0);
        }
    }

    int orow0 = blockIdx.x * 64 + wave * 16 + (lane >> 4) * 4;
    #pragma unroll
    for (int cf = 0; cf < 8; ++cf) {
        int ocol = cf * 16 + lsel;
        float bv = bias[ocol];
        #pragma unroll
        for (int r = 0; r < 4; ++r) {
            int orow = orow0 + r;
            if (orow < N) out[(long)orow * C + ocol] = acc[cf][r] + bv;
        }
    }
}

extern "C" void kernel_launch(void* const* d_in, const int* in_sizes, int n_in,
                              void* d_out, int out_size, void* d_ws, size_t ws_size,
                              hipStream_t stream) {
    const float* x          = (const float*)d_in[0];
    const int*   ei         = (const int*)d_in[1];   // harness delivers int32
    const float* W          = (const float*)d_in[3];
    const float* bias       = (const float*)d_in[4];
    const float* log_scale  = (const float*)d_in[5];
    const float* hop_logits = (const float*)d_in[6];
    float* out = (float*)d_out;

    int N = in_sizes[0] / C;
    int E = in_sizes[1] / 2;

    char* ws = (char*)d_ws;
    size_t hb = (size_t)N * C * sizeof(unsigned short);   // 25.6 MB per bf16 hop buffer
    unsigned short* h1 = (unsigned short*)ws;
    unsigned short* h2 = (unsigned short*)(ws + hb);
    unsigned short* h3 = (unsigned short*)(ws + 2 * hb);
    int2*  ell     = (int2*)(ws + 3 * hb);                // N*WELL entries = 25.6 MB
    int*   degs    = (int*)(ell + (long)N * WELL);        // [degs | degd | cursor] contiguous
    int*   degd    = degs + N;
    int*   cursor  = degd + N;
    float* coef    = (float*)(cursor + N);
    unsigned short* WtB = (unsigned short*)(coef + 4);    // 128*128 bf16

    int eb4 = (E / 4 + 255) / 256 + 1;    // 4 edges/thread kernels
    int pull_blocks = (int)(((long)N * 64 + 255) / 256);

    // build: zero counts -> histograms -> Wt/coef -> ELL scatter (no scan needed)
    zero_int_kernel<<<(int)((3L * N / 4 + 255) / 256), 256, 0, stream>>>((int4*)degs, 3L * N / 4);
    hist_kernel<<<eb4, 256, 0, stream>>>(ei, E, degs, degd);
    wt_kernel<<<64, 256, 0, stream>>>(W, WtB, log_scale, hop_logits, coef);
    scatter_kernel<<<eb4, 256, 0, stream>>>(ei, E, cursor, degs, ell);

    // hops: predicated 8-wide gather -> bf16 write
    pull_kernel<1><<<pull_blocks, 256, 0, stream>>>(ell, degd, x,  (unsigned int*)h1, N);
    pull_kernel<0><<<pull_blocks, 256, 0, stream>>>(ell, degd, h1, (unsigned int*)h2, N);
    pull_kernel<0><<<pull_blocks, 256, 0, stream>>>(ell, degd, h2, (unsigned int*)h3, N);

    // out = (c0*x + c1*h1 + c2*h2 + c3*h3) @ W + bias  (MFMA)
    mfma_matmul_kernel<<<(N + 63) / 64, 256, 0, stream>>>(x, h1, h2, h3, coef, WtB, bias, out, N);
}

// Round 10
// 247.571 us; speedup vs baseline: 1.1060x; 1.0616x over previous
//
#include <hip/hip_runtime.h>
#include <hip/hip_bf16.h>

#define C 128

typedef short s16x8 __attribute__((ext_vector_type(8)));
typedef float f32x4 __attribute__((ext_vector_type(4)));

static __device__ __forceinline__ float b2f(unsigned short u) {
    union { unsigned int i; float f; } v;
    v.i = ((unsigned int)u) << 16;
    return v.f;
}
static __device__ __forceinline__ unsigned short f2b(float f) {
    __hip_bfloat16 b = __float2bfloat16(f);   // RNE
    return *reinterpret_cast<unsigned short*>(&b);
}

// ---------------- zero ints (int4) ----------------
__global__ __launch_bounds__(256) void zero_int_kernel(int4* __restrict__ p, long n4) {
    long i = blockIdx.x * 256L + threadIdx.x;
    if (i < n4) p[i] = make_int4(0, 0, 0, 0);
}

// ---------------- degree histograms, 4 edges/thread ----------------
__global__ __launch_bounds__(256) void hist_kernel(
    const int* __restrict__ ei, int E,
    int* __restrict__ degs, int* __restrict__ degd) {
    int i = blockIdx.x * 256 + threadIdx.x;
    int e0 = i * 4;
    if (e0 + 4 <= E) {
        int4 s = *(const int4*)(ei + e0);
        int4 d = *(const int4*)(ei + E + e0);
        atomicAdd(&degs[s.x], 1); atomicAdd(&degs[s.y], 1);
        atomicAdd(&degs[s.z], 1); atomicAdd(&degs[s.w], 1);
        atomicAdd(&degd[d.x], 1); atomicAdd(&degd[d.y], 1);
        atomicAdd(&degd[d.z], 1); atomicAdd(&degd[d.w], 1);
    } else {
        for (int e = e0; e < E; ++e) {
            atomicAdd(&degs[ei[e]], 1);
            atomicAdd(&degd[ei[E + e]], 1);
        }
    }
}

// ---------------- W transpose -> bf16 + coef (one-time, tiny) ----------------
__global__ __launch_bounds__(256) void wt_kernel(const float* __restrict__ W,
                                                 unsigned short* __restrict__ WtB,
                                                 const float* __restrict__ log_scale,
                                                 const float* __restrict__ hop_logits,
                                                 float* __restrict__ coef) {
    int tid = blockIdx.x * 256 + threadIdx.x;   // 16384 threads
    int k = tid & 127, c = tid >> 7;
    WtB[c * 128 + k] = f2b(W[k * 128 + c]);
    if (tid == 0) {
        float s = expf(log_scale[0]);
        float m = hop_logits[0];
        for (int kk = 1; kk < 4; ++kk) m = fmaxf(m, hop_logits[kk]);
        float a[4], sum = 0.0f;
        for (int kk = 0; kk < 4; ++kk) { a[kk] = expf(hop_logits[kk] - m); sum += a[kk]; }
        for (int kk = 0; kk < 4; ++kk) coef[kk] = (a[kk] / sum) * expf(-s * (float)kk);
    }
}

// ---------------- scan stage 1 ----------------
__global__ __launch_bounds__(256) void scan1_kernel(const int* __restrict__ degd,
                                                    int* __restrict__ rp,
                                                    int* __restrict__ bsum, int N) {
    __shared__ int sm[256];
    int t = threadIdx.x;
    int i = blockIdx.x * 256 + t;
    int v = (i < N) ? degd[i] : 0;
    sm[t] = v;
    __syncthreads();
    for (int off = 1; off < 256; off <<= 1) {
        int add = (t >= off) ? sm[t - off] : 0;
        __syncthreads();
        sm[t] += add;
        __syncthreads();
    }
    if (i < N) rp[i] = sm[t] - v;
    if (t == 255) bsum[blockIdx.x] = sm[255];
}

// ---------------- scan stage 2 ----------------
__global__ __launch_bounds__(512) void scan2_kernel(int* __restrict__ bsum, int nb) {
    __shared__ int sm[512];
    int t = threadIdx.x;
    int v = (t < nb) ? bsum[t] : 0;
    sm[t] = v;
    __syncthreads();
    for (int off = 1; off < 512; off <<= 1) {
        int add = (t >= off) ? sm[t - off] : 0;
        __syncthreads();
        sm[t] += add;
        __syncthreads();
    }
    if (t < nb) bsum[t] = sm[t] - v;
}

// ---------------- scan stage 3: offsets + cursor + dsi/ddi; rp[N]=E ----------------
__global__ __launch_bounds__(256) void scan3_kernel(int* __restrict__ rp,
                                                    const int* __restrict__ bsum,
                                                    int* __restrict__ cursor,
                                                    const int* __restrict__ degs,
                                                    const int* __restrict__ degd,
                                                    float* __restrict__ dsi,
                                                    float* __restrict__ ddi,
                                                    int N, int E) {
    int i = blockIdx.x * 256 + threadIdx.x;
    if (i < N) {
        int v = rp[i] + bsum[i >> 8];
        rp[i] = v;
        cursor[i] = v;
        int ds = degs[i];
        dsi[i] = ds > 0 ? rsqrtf((float)ds) : 0.0f;
        int dd = degd[i];
        ddi[i] = dd > 0 ? rsqrtf((float)dd) : 0.0f;
    }
    if (i == 0) rp[N] = E;
}

// ---------------- scatter edges into CSR (by dst), 4 edges/thread ----------------
__global__ __launch_bounds__(256) void scatter_kernel(const int* __restrict__ ei, int E,
                                                      int* __restrict__ cursor,
                                                      const float* __restrict__ dsi,
                                                      int2* __restrict__ csr) {
    int i = blockIdx.x * 256 + threadIdx.x;
    int e0 = i * 4;
    if (e0 + 4 <= E) {
        int4 s = *(const int4*)(ei + e0);
        int4 d = *(const int4*)(ei + E + e0);
        float w0 = dsi[s.x], w1 = dsi[s.y], w2 = dsi[s.z], w3 = dsi[s.w];
        int p0 = atomicAdd(&cursor[d.x], 1);
        int p1 = atomicAdd(&cursor[d.y], 1);
        int p2 = atomicAdd(&cursor[d.z], 1);
        int p3 = atomicAdd(&cursor[d.w], 1);
        csr[p0] = make_int2(s.x, __float_as_int(w0));
        csr[p1] = make_int2(s.y, __float_as_int(w1));
        csr[p2] = make_int2(s.z, __float_as_int(w2));
        csr[p3] = make_int2(s.w, __float_as_int(w3));
    } else {
        for (int e = e0; e < E; ++e) {
            int s = ei[e];
            int d = ei[E + e];
            int pos = atomicAdd(&cursor[d], 1);
            csr[pos] = make_int2(s, __float_as_int(dsi[s]));
        }
    }
}

// ---------------- pull-mode hop: one wave per dst node, 8-wide predicated ----------------
template<int SRCF32>
__global__ __launch_bounds__(256) void pull_kernel(
    const int* __restrict__ rp, const int2* __restrict__ csr,
    const float* __restrict__ ddi,
    const void* __restrict__ cur, unsigned int* __restrict__ nxt, int N) {
    int wid = (int)((blockIdx.x * 256L + threadIdx.x) >> 6);
    if (wid >= N) return;
    int lane = threadIdx.x & 63;
    int beg = __builtin_amdgcn_readfirstlane(rp[wid]);
    int end = __builtin_amdgcn_readfirstlane(rp[wid + 1]);
    const float2* curf = (const float2*)cur;
    const unsigned int* curb = (const unsigned int*)cur;
    float sx = 0.f, sy = 0.f;
    if (beg < end) {
        for (int j = beg; j < end; j += 8) {
            int   idx[8];
            float wt[8];
            #pragma unroll
            for (int i = 0; i < 8; ++i) {
                int jj = j + i;
                bool ok = jj < end;
                int2 e = csr[ok ? jj : beg];
                idx[i] = e.x;
                wt[i] = ok ? __int_as_float(e.y) : 0.0f;
            }
            if (SRCF32) {
                float2 v[8];
                #pragma unroll
                for (int i = 0; i < 8; ++i) v[i] = curf[(long)idx[i] * 64 + lane];
                #pragma unroll
                for (int i = 0; i < 8; ++i) { sx += wt[i] * v[i].x; sy += wt[i] * v[i].y; }
            } else {
                unsigned int u[8];
                #pragma unroll
                for (int i = 0; i < 8; ++i) u[i] = curb[(long)idx[i] * 64 + lane];
                #pragma unroll
                for (int i = 0; i < 8; ++i) {
                    sx += wt[i] * b2f((unsigned short)(u[i] & 0xffff));
                    sy += wt[i] * b2f((unsigned short)(u[i] >> 16));
                }
            }
        }
        float dv = ddi[wid];
        sx *= dv; sy *= dv;
    }
    unsigned int o = (unsigned int)f2b(sx) | ((unsigned int)f2b(sy) << 16);
    nxt[(long)wid * 64 + lane] = o;
}

// ---------------- pull hop 3 + combine: hc = bf16(c0*x + c1*h1 + c2*h2 + c3*h3) ----------------
// gather h3[wid] from h2 (registers), stream own x/h1/h2 rows, write combined bf16 row.
// No sync, no MFMA: pure independent-wave kernel.
__global__ __launch_bounds__(256) void pull3c_kernel(
    const int* __restrict__ rp, const int2* __restrict__ csr,
    const float* __restrict__ ddi,
    const float* __restrict__ x,
    const unsigned short* __restrict__ h1,
    const unsigned short* __restrict__ h2,
    const float* __restrict__ coef,
    unsigned int* __restrict__ hc, int N) {
    int wid = (int)((blockIdx.x * 256L + threadIdx.x) >> 6);
    if (wid >= N) return;
    int lane = threadIdx.x & 63;
    int beg = __builtin_amdgcn_readfirstlane(rp[wid]);
    int end = __builtin_amdgcn_readfirstlane(rp[wid + 1]);
    const unsigned int* curb = (const unsigned int*)h2;
    float sx = 0.f, sy = 0.f;
    if (beg < end) {
        for (int j = beg; j < end; j += 8) {
            int   idx[8];
            float wt[8];
            #pragma unroll
            for (int i = 0; i < 8; ++i) {
                int jj = j + i;
                bool ok = jj < end;
                int2 e = csr[ok ? jj : beg];
                idx[i] = e.x;
                wt[i] = ok ? __int_as_float(e.y) : 0.0f;
            }
            unsigned int u[8];
            #pragma unroll
            for (int i = 0; i < 8; ++i) u[i] = curb[(long)idx[i] * 64 + lane];
            #pragma unroll
            for (int i = 0; i < 8; ++i) {
                sx += wt[i] * b2f((unsigned short)(u[i] & 0xffff));
                sy += wt[i] * b2f((unsigned short)(u[i] >> 16));
            }
        }
        float dv = ddi[wid];
        sx *= dv; sy *= dv;
    }
    // combine with own rows (sequential reads)
    float c0 = coef[0], c1 = coef[1], c2 = coef[2], c3 = coef[3];
    long rbase = (long)wid * C;
    float2 xv = ((const float2*)(x + rbase))[lane];
    unsigned int u1 = ((const unsigned int*)(h1 + rbase))[lane];
    unsigned int u2 = ((const unsigned int*)(h2 + rbase))[lane];
    float f0 = c0 * xv.x + c1 * b2f((unsigned short)(u1 & 0xffff))
             + c2 * b2f((unsigned short)(u2 & 0xffff)) + c3 * sx;
    float f1 = c0 * xv.y + c1 * b2f((unsigned short)(u1 >> 16))
             + c2 * b2f((unsigned short)(u2 >> 16)) + c3 * sy;
    hc[(long)wid * 64 + lane] = (unsigned int)f2b(f0) | ((unsigned int)f2b(f1) << 16);
}

// ---------------- pure MFMA GEMM: out = hc @ W + bias ----------------
// 64 rows/block, 4 waves; A loads directly from hc (bf16); B (W^T) in LDS (136-padded).
__global__ __launch_bounds__(256) void gemm_kernel(
    const unsigned short* __restrict__ hc,
    const unsigned short* __restrict__ WtB,
    const float* __restrict__ bias,
    float* __restrict__ out, int N) {
    __shared__ unsigned short Wl[128 * 136];   // 34816 B, padded rows
    int t = threadIdx.x;

    #pragma unroll
    for (int i = 0; i < 8; ++i) {
        int ch = t + i * 256;          // 0..2047
        int r = ch >> 4;               // 0..127 (col of W)
        int ko = (ch & 15) * 8;        // k offset
        *(s16x8*)(Wl + r * 136 + ko) = *(const s16x8*)(WtB + r * 128 + ko);
    }
    __syncthreads();

    int wave = t >> 6, lane = t & 63;
    int lsel = lane & 15;
    int lk   = (lane >> 4) * 8;
    int arow = blockIdx.x * 64 + wave * 16 + lsel;
    bool rok = arow < N;
    long rbase = (long)arow * C;

    f32x4 acc[8];
    #pragma unroll
    for (int i = 0; i < 8; ++i) acc[i] = (f32x4){0.f, 0.f, 0.f, 0.f};

    #pragma unroll
    for (int ks = 0; ks < 4; ++ks) {
        int k0 = ks * 32 + lk;
        s16x8 a = rok ? *(const s16x8*)(hc + rbase + k0) : (s16x8)0;
        #pragma unroll
        for (int cf = 0; cf < 8; ++cf) {
            s16x8 b = *(const s16x8*)(Wl + (cf * 16 + lsel) * 136 + k0);
            acc[cf] = __builtin_amdgcn_mfma_f32_16x16x32_bf16(a, b, acc[cf], 0, 0, 0);
        }
    }

    int orow0 = blockIdx.x * 64 + wave * 16 + (lane >> 4) * 4;
    #pragma unroll
    for (int cf = 0; cf < 8; ++cf) {
        int ocol = cf * 16 + lsel;
        float bv = bias[ocol];
        #pragma unroll
        for (int r = 0; r < 4; ++r) {
            int orow = orow0 + r;
            if (orow < N) out[(long)orow * C + ocol] = acc[cf][r] + bv;
        }
    }
}

extern "C" void kernel_launch(void* const* d_in, const int* in_sizes, int n_in,
                              void* d_out, int out_size, void* d_ws, size_t ws_size,
                              hipStream_t stream) {
    const float* x          = (const float*)d_in[0];
    const int*   ei         = (const int*)d_in[1];   // harness delivers int32
    const float* W          = (const float*)d_in[3];
    const float* bias       = (const float*)d_in[4];
    const float* log_scale  = (const float*)d_in[5];
    const float* hop_logits = (const float*)d_in[6];
    float* out = (float*)d_out;

    int N = in_sizes[0] / C;
    int E = in_sizes[1] / 2;

    char* ws = (char*)d_ws;
    size_t hb = (size_t)N * C * sizeof(unsigned short);   // 25.6 MB per bf16 buffer
    unsigned short* h1 = (unsigned short*)ws;
    unsigned short* h2 = (unsigned short*)(ws + hb);
    unsigned short* hc = (unsigned short*)(ws + 2 * hb);  // combined row buffer
    int2*  csr     = (int2*)(ws + 3 * hb);                // E entries
    int*   degs    = (int*)(csr + E);
    int*   degd    = degs + N;
    int*   rp      = degd + N;            // N+1
    int*   cursor  = rp + N + 1;
    float* dsi     = (float*)(cursor + N);
    float* ddi     = dsi + N;
    int*   bsum    = (int*)(ddi + N);     // 512
    float* coef    = (float*)(bsum + 512);
    unsigned short* WtB = (unsigned short*)(coef + 4);    // 128*128 bf16

    int eb4 = (E / 4 + 255) / 256 + 1;    // 4 edges/thread kernels
    int nbk = (N + 255) / 256;
    int pull_blocks = (int)(((long)N * 64 + 255) / 256);

    // CSR build
    zero_int_kernel<<<(int)((2L * N / 4 + 255) / 256), 256, 0, stream>>>((int4*)degs, 2L * N / 4);
    hist_kernel<<<eb4, 256, 0, stream>>>(ei, E, degs, degd);
    wt_kernel<<<64, 256, 0, stream>>>(W, WtB, log_scale, hop_logits, coef);
    scan1_kernel<<<nbk, 256, 0, stream>>>(degd, rp, bsum, N);
    scan2_kernel<<<1, 512, 0, stream>>>(bsum, nbk);
    scan3_kernel<<<nbk, 256, 0, stream>>>(rp, bsum, cursor, degs, degd, dsi, ddi, N, E);
    scatter_kernel<<<eb4, 256, 0, stream>>>(ei, E, cursor, dsi, csr);

    // hops 1,2: predicated 8-wide gather -> bf16 write
    pull_kernel<1><<<pull_blocks, 256, 0, stream>>>(rp, csr, ddi, x,  (unsigned int*)h1, N);
    pull_kernel<0><<<pull_blocks, 256, 0, stream>>>(rp, csr, ddi, h1, (unsigned int*)h2, N);

    // hop 3 fused with combine (no sync, no MFMA): hc = bf16(c0*x+c1*h1+c2*h2+c3*h3)
    pull3c_kernel<<<pull_blocks, 256, 0, stream>>>(rp, csr, ddi, x, h1, h2, coef,
                                                   (unsigned int*)hc, N);

    // out = hc @ W + bias  (pure MFMA GEMM, 25.6 MB input)
    gemm_kernel<<<(N + 63) / 64, 256, 0, stream>>>(hc, WtB, bias, out, N);
}